// Round 18
// baseline (108.361 us; speedup 1.0000x reference)
//
#include <hip/hip_runtime.h>
#include <hip/hip_bf16.h>

// MaskedSelfAttention: B=2, S=2048, D=1024, H=16, depth=64.
// prep(weights only) -> QKV GEMM (128x192, A-side converts x f32->bf16
// inline during reg-staging; fragment-layout K/V epilogue) -> flash attn
// (LDS-free, fixed-max softmax, 1152 k-split chunks) -> combine+vmean ->
// out GEMM (64x128).
// R18: x-convert fused into QKV A-staging (reg-stage: load f32, cvt,
// swizzled ds_write). Removes prep's x pass (24MB) and the xb buffer.

using bf16   = __bf16;
using bf16x2 = __attribute__((ext_vector_type(2))) __bf16;
using bf16x4 = __attribute__((ext_vector_type(4))) __bf16;
using bf16x8 = __attribute__((ext_vector_type(8))) __bf16;
using f32x4  = __attribute__((ext_vector_type(4))) float;
using uintx2 = __attribute__((ext_vector_type(2))) unsigned int;
using uintx4 = __attribute__((ext_vector_type(4))) unsigned int;

#define ATTN_LOG2E 1.4426950408889634f
#define ATTN_MBIAS (-11.541560327111707f)  // -8 * log2(e)

__device__ __forceinline__ void load_lds16(const void* g, void* l) {
  __builtin_amdgcn_global_load_lds(
      (const __attribute__((address_space(1))) void*)g,
      (__attribute__((address_space(3))) void*)l, 16, 0, 0);
}

__device__ __forceinline__ unsigned int packbf(float a, float b) {
  bf16x2 v;
  v[0] = (bf16)a;
  v[1] = (bf16)b;
  return __builtin_bit_cast(unsigned int, v);
}

// Redistribute packed P words across hi-groups (in-register P, R4).
__device__ __forceinline__ void xchg_p(unsigned int u, unsigned int v, int hi,
                                       unsigned int& f, unsigned int& s) {
#if __has_builtin(__builtin_amdgcn_permlane32_swap) && \
    __has_builtin(__builtin_amdgcn_permlane16_swap)
  uintx2 ab = __builtin_amdgcn_permlane32_swap(u, v, false, false);
  uintx2 fs = __builtin_amdgcn_permlane16_swap(ab[0], ab[1], false, false);
  f = fs[0];
  s = fs[1];
#else
  unsigned int a = (hi < 2) ? u : (unsigned int)__shfl_xor((int)v, 32);
  unsigned int b = (hi < 2) ? (unsigned int)__shfl_xor((int)u, 32) : v;
  unsigned int a16 = (unsigned int)__shfl_xor((int)a, 16);
  unsigned int b16 = (unsigned int)__shfl_xor((int)b, 16);
  f = (hi & 1) ? b16 : a;
  s = (hi & 1) ? b : a16;
#endif
}

// attn chunk table: jq | kbeg<<8 | kend<<16 | slot<<24
__device__ const unsigned int kChunkTab[36] = {
    0u  | (0u << 8)  | (11u << 16) | (0u << 24),   // 11
    0u  | (11u << 8) | (22u << 16) | (1u << 24),   // 11
    0u  | (22u << 8) | (32u << 16) | (2u << 24),   // 10
    1u  | (2u << 8)  | (12u << 16) | (0u << 24),   // 10
    1u  | (12u << 8) | (22u << 16) | (1u << 24),   // 10
    1u  | (22u << 8) | (32u << 16) | (2u << 24),   // 10
    2u  | (4u << 8)  | (14u << 16) | (0u << 24),   // 10
    2u  | (14u << 8) | (23u << 16) | (1u << 24),   // 9
    2u  | (23u << 8) | (32u << 16) | (2u << 24),   // 9
    3u  | (6u << 8)  | (15u << 16) | (0u << 24),   // 9
    3u  | (15u << 8) | (24u << 16) | (1u << 24),   // 9
    4u  | (8u << 8)  | (16u << 16) | (0u << 24),   // 8
    4u  | (16u << 8) | (24u << 16) | (1u << 24),   // 8
    4u  | (24u << 8) | (32u << 16) | (2u << 24),   // 8
    8u  | (16u << 8) | (24u << 16) | (0u << 24),   // 8
    8u  | (24u << 8) | (32u << 16) | (1u << 24),   // 8
    12u | (24u << 8) | (32u << 16) | (3u << 24),   // 8 final
    3u  | (24u << 8) | (32u << 16) | (2u << 24),   // 8
    5u  | (10u << 8) | (18u << 16) | (0u << 24),   // 8
    5u  | (18u << 8) | (25u << 16) | (1u << 24),   // 7
    5u  | (25u << 8) | (32u << 16) | (2u << 24),   // 7
    6u  | (12u << 8) | (19u << 16) | (0u << 24),   // 7
    6u  | (19u << 8) | (26u << 16) | (1u << 24),   // 7
    9u  | (18u << 8) | (25u << 16) | (0u << 24),   // 7
    9u  | (25u << 8) | (32u << 16) | (1u << 24),   // 7
    6u  | (26u << 8) | (32u << 16) | (2u << 24),   // 6
    7u  | (14u << 8) | (20u << 16) | (0u << 24),   // 6
    7u  | (20u << 8) | (26u << 16) | (1u << 24),   // 6
    7u  | (26u << 8) | (32u << 16) | (2u << 24),   // 6
    10u | (20u << 8) | (26u << 16) | (0u << 24),   // 6
    10u | (26u << 8) | (32u << 16) | (1u << 24),   // 6
    13u | (26u << 8) | (32u << 16) | (3u << 24),   // 6 final
    11u | (22u << 8) | (27u << 16) | (0u << 24),   // 5
    11u | (27u << 8) | (32u << 16) | (1u << 24),   // 5
    14u | (28u << 8) | (32u << 16) | (3u << 24),   // 4 final
    15u | (30u << 8) | (32u << 16) | (3u << 24)};  // 2 final

// ---------------- prep: transpose 4 weights (f32 [k][n] -> bf16 [n][k]) ---
__global__ __launch_bounds__(256) void prep_kernel(
    const float* __restrict__ wq, const float* __restrict__ wk,
    const float* __restrict__ wv, const float* __restrict__ wo,
    bf16* __restrict__ wT) {
  const int t = threadIdx.x;
  const int bid = blockIdx.x;
  const int sel = bid >> 8;  // 0..3 : wq wk wv wo
  const float* w = (sel == 0) ? wq : (sel == 1) ? wk : (sel == 2) ? wv : wo;
  bf16* out = wT + (size_t)sel * 1048576;
  __shared__ float tile[64][65];
  const int n0 = (bid & 15) * 64;
  const int k0 = ((bid >> 4) & 15) * 64;
#pragma unroll
  for (int p = 0; p < 4; ++p) {
    const int row = p * 16 + (t >> 4);
    const int c4  = (t & 15) * 4;
    const float4 v = *(const float4*)&w[(size_t)(k0 + row) * 1024 + n0 + c4];
    tile[row][c4 + 0] = v.x; tile[row][c4 + 1] = v.y;
    tile[row][c4 + 2] = v.z; tile[row][c4 + 3] = v.w;
  }
  __syncthreads();
#pragma unroll
  for (int p = 0; p < 4; ++p) {
    const int rn = p * 16 + (t >> 4);
    const int c4 = (t & 15) * 4;
    bf16x4 o;
#pragma unroll
    for (int j = 0; j < 4; ++j) o[j] = (bf16)tile[c4 + j][rn];
    *(bf16x4*)&out[(size_t)(n0 + rn) * 1024 + k0 + c4] = o;
  }
}

// ---------------- QKV GEMM: 128x192 tiles, 512 blocks @ 2/CU -------------
// C = x[4096][1024](f32, converted inline) * Bt[3072][1024]^T; epilogue
// scatters Q flat / K frag / V frag (+bias), branching per column n.
__global__ __launch_bounds__(256, 2) void gemm_qkv(
    const float* __restrict__ x, const bf16* __restrict__ Bt,
    const float* __restrict__ bias0, const float* __restrict__ bias1,
    const float* __restrict__ bias2, bf16* __restrict__ qf,
    bf16* __restrict__ kfr, bf16* __restrict__ vfr) {
  __shared__ __align__(16) char smem[40960];  // sA 128x128B | sB 192x128B
  char* sA = smem;
  char* sB = smem + 16384;
  const int tid = threadIdx.x;
  const int lane = tid & 63;
  const int qlo = lane & 15;
  const int hi = lane >> 4;
  const int w = tid >> 6;
  const int wm = w >> 1, wn = w & 1;
  const int bid = blockIdx.x;
  const int m0 = (bid >> 4) * 128;
  const int n0 = (bid & 15) * 192;

  const char* Bb = (const char*)Bt;
  const int r_ = tid >> 3;
  const int ac = tid & 7;  // logical 16B(bf16)=32B(f32) chunk within row
  // A-side: x source rows + swizzled LDS dests (write-side swizzle)
  const float* xsrc[4];
  char* adst[4];
#pragma unroll
  for (int i = 0; i < 4; ++i) {
    const int r = i * 32 + r_;
    xsrc[i] = x + (size_t)(m0 + r) * 1024 + ac * 8;
    adst[i] = sA + r * 128 + ((ac ^ (r & 7)) << 4);
  }
  // B-side: pre-swizzled global sources for global_load_lds
  size_t srcB[6];
#pragma unroll
  for (int i = 0; i < 6; ++i) {
    const int r = i * 32 + r_;
    const int cg = ac ^ (r & 7);
    srcB[i] = (size_t)(n0 + r) * 2048 + cg * 16;
  }

  f32x4 acc[4][6] = {};

  for (int kt = 0; kt < 16; ++kt) {
    const size_t kb = (size_t)kt * 128;
    // B staging first (async DMA), overlaps with A reg-convert below
#pragma unroll
    for (int i = 0; i < 6; ++i)
      load_lds16(Bb + srcB[i] + kb, sB + i * 4096 + tid * 16);
    // A staging: load x f32, convert, swizzled ds_write
#pragma unroll
    for (int i = 0; i < 4; ++i) {
      const float4 f0 = *(const float4*)(xsrc[i] + kt * 64);
      const float4 f1 = *(const float4*)(xsrc[i] + kt * 64 + 4);
      bf16x8 v8;
      v8[0] = (bf16)f0.x; v8[1] = (bf16)f0.y;
      v8[2] = (bf16)f0.z; v8[3] = (bf16)f0.w;
      v8[4] = (bf16)f1.x; v8[5] = (bf16)f1.y;
      v8[6] = (bf16)f1.z; v8[7] = (bf16)f1.w;
      *(bf16x8*)adst[i] = v8;
    }
    __syncthreads();  // drains vm (B DMA + x loads) and lgkm (ds_writes)
#pragma unroll
    for (int ks = 0; ks < 2; ++ks) {
      const int g = hi + 4 * ks;
      bf16x8 aF[4], bF[6];
#pragma unroll
      for (int mi = 0; mi < 4; ++mi) {
        const int ra = wm * 64 + mi * 16 + qlo;
        aF[mi] = *(const bf16x8*)(sA + ra * 128 + ((g ^ (ra & 7)) << 4));
      }
#pragma unroll
      for (int ni = 0; ni < 6; ++ni) {
        const int rb = wn * 96 + ni * 16 + qlo;
        bF[ni] = *(const bf16x8*)(sB + rb * 128 + ((g ^ (rb & 7)) << 4));
      }
#pragma unroll
      for (int mi = 0; mi < 4; ++mi)
#pragma unroll
        for (int ni = 0; ni < 6; ++ni)
          acc[mi][ni] = __builtin_amdgcn_mfma_f32_16x16x32_bf16(
              aF[mi], bF[ni], acc[mi][ni], 0, 0, 0);
    }
    __syncthreads();
  }

#pragma unroll
  for (int mi = 0; mi < 4; ++mi) {
#pragma unroll
    for (int ni = 0; ni < 6; ++ni) {
      const int n  = n0 + wn * 96 + ni * 16 + qlo;
      const int mb = m0 + wm * 64 + mi * 16 + 4 * hi;
      const f32x4 v = acc[mi][ni];
      const float bias =
          (n < 1024) ? bias0[n] : ((n < 2048) ? bias1[n - 1024] : bias2[n - 2048]);
      if (n < 1024) {  // Q flat
#pragma unroll
        for (int j = 0; j < 4; ++j)
          qf[(size_t)(mb + j) * 1024 + n] = (bf16)(v[j] + bias);
      } else if (n < 2048) {  // K fragment layout
        const int dg = n - 1024;
        const int hh = dg >> 6, d = dg & 63;
        const int ks = d >> 5, hl = (d >> 3) & 3, e = d & 7;
        const int bb = mb >> 11, sl = mb & 2047;
        const int ktt = sl >> 6, tt = (sl >> 4) & 3, ql = sl & 15;
        bf16* dst = kfr +
                    ((((size_t)(bb * 16 + hh) * 32 + ktt) * 4 + tt) * 2 + ks) *
                        512 +
                    (hl * 16 + ql) * 8 + e;
#pragma unroll
        for (int j = 0; j < 4; ++j) dst[j * 8] = (bf16)(v[j] + bias);
      } else {  // V fragment layout (8B packed store)
        const int dg = n - 2048;
        const int hh = dg >> 6, d = dg & 63;
        const int dt = d >> 4, dc = d & 15;
        const int bb = mb >> 11, sl = mb & 2047;
        const int ktt = sl >> 6, ks = (sl >> 5) & 1, hl = (sl >> 3) & 3,
                  e0 = sl & 7;
        bf16x4 pk;
#pragma unroll
        for (int j = 0; j < 4; ++j) pk[j] = (bf16)(v[j] + bias);
        *(bf16x4*)(vfr +
                   ((((size_t)(bb * 16 + hh) * 32 + ktt) * 4 + dt) * 2 + ks) *
                       512 +
                   (hl * 16 + dc) * 8 + e0) = pk;
      }
    }
  }
}

// ---------------- out GEMM: 64x128 tiles, 512 blocks @ 2/CU --------------
__global__ __launch_bounds__(256, 2) void gemm_out(
    const bf16* __restrict__ A, const bf16* __restrict__ Bt,
    const float* __restrict__ bias0, float* __restrict__ fout) {
  __shared__ __align__(16) char smem[24576];  // sA 64x128B | sB 128x128B
  char* sA = smem;
  char* sB = smem + 8192;
  const int tid = threadIdx.x;
  const int lane = tid & 63;
  const int qlo = lane & 15;
  const int hi = lane >> 4;
  const int w = tid >> 6;
  const int wm = w >> 1, wn = w & 1;  // 2m x 2n waves
  const int bid = blockIdx.x;
  const int m0 = (bid >> 3) * 64;
  const int n0 = (bid & 7) * 128;

  const char* Ab = (const char*)A;
  const char* Bb = (const char*)Bt;
  const int r_ = tid >> 3;
  size_t srcA[2], srcB[4];
#pragma unroll
  for (int i = 0; i < 2; ++i) {
    const int r = r_ + i * 32;
    const int cg = (tid & 7) ^ (r & 7);
    srcA[i] = (size_t)(m0 + r) * 2048 + cg * 16;
  }
#pragma unroll
  for (int i = 0; i < 4; ++i) {
    const int r = r_ + i * 32;
    const int cg = (tid & 7) ^ (r & 7);
    srcB[i] = (size_t)(n0 + r) * 2048 + cg * 16;
  }

  f32x4 acc[2][4] = {};

  for (int kt = 0; kt < 16; ++kt) {
    const size_t kb = (size_t)kt * 128;
#pragma unroll
    for (int i = 0; i < 2; ++i)
      load_lds16(Ab + srcA[i] + kb, sA + i * 4096 + tid * 16);
#pragma unroll
    for (int i = 0; i < 4; ++i)
      load_lds16(Bb + srcB[i] + kb, sB + i * 4096 + tid * 16);
    asm volatile("s_waitcnt vmcnt(0)" ::: "memory");
    __syncthreads();
#pragma unroll
    for (int ks = 0; ks < 2; ++ks) {
      const int g = hi + 4 * ks;
      bf16x8 aF[2], bF[4];
#pragma unroll
      for (int mi = 0; mi < 2; ++mi) {
        const int ra = wm * 32 + mi * 16 + qlo;
        aF[mi] = *(const bf16x8*)(sA + ra * 128 + ((g ^ (ra & 7)) << 4));
      }
#pragma unroll
      for (int ni = 0; ni < 4; ++ni) {
        const int rb = wn * 64 + ni * 16 + qlo;
        bF[ni] = *(const bf16x8*)(sB + rb * 128 + ((g ^ (rb & 7)) << 4));
      }
#pragma unroll
      for (int mi = 0; mi < 2; ++mi)
#pragma unroll
        for (int ni = 0; ni < 4; ++ni)
          acc[mi][ni] = __builtin_amdgcn_mfma_f32_16x16x32_bf16(
              aF[mi], bF[ni], acc[mi][ni], 0, 0, 0);
    }
    __syncthreads();
  }

#pragma unroll
  for (int mi = 0; mi < 2; ++mi) {
#pragma unroll
    for (int ni = 0; ni < 4; ++ni) {
      const int n  = n0 + wn * 64 + ni * 16 + qlo;
      const int mb = m0 + wm * 32 + mi * 16 + 4 * hi;
      const f32x4 v = acc[mi][ni];
      const float bias = bias0[n];
#pragma unroll
      for (int j = 0; j < 4; ++j)
        fout[(size_t)(mb + j) * 1024 + n] = v[j] + bias;
    }
  }
}

// ---------------- flash attention v15 (valid keys: k > q) ----------------
__global__ __launch_bounds__(256, 2) void attn_kernel(
    const bf16* __restrict__ qf, const bf16* __restrict__ kfr,
    const bf16* __restrict__ vfr, bf16* __restrict__ ao,
    bf16* __restrict__ sc1, bf16* __restrict__ sc2,
    float* __restrict__ lbuf) {
  const int tid  = threadIdx.x;
  const int lane = tid & 63;
  const int hi   = lane >> 4;
  const int qlo  = lane & 15;
  const int w    = tid >> 6;
  const int u  = blockIdx.x >> 5;  // 0..35
  const int bh = blockIdx.x & 31;  // same-bh blocks share an XCD's L2
  const int b = bh >> 4, h = bh & 15;

  const unsigned int ent = kChunkTab[u];
  const int jq = ent & 255, kbeg = (ent >> 8) & 255, kend = (ent >> 16) & 255;
  const int slot = ent >> 24;

  const char* kfb = (const char*)kfr + (size_t)bh * 262144 + lane * 16;
  const char* vfb = (const char*)vfr + (size_t)bh * 262144 + lane * 16;
  const char* qbb = (const char*)qf + ((size_t)b * 2048) * 2048 + h * 128;

  bf16x8 onesB;
#pragma unroll
  for (int i = 0; i < 8; ++i) onesB[i] = (bf16)1.0f;

  const int q0 = jq * 128;
  const int qb = q0 + w * 32;

  // Q fragments for 2 column-tiles (pre-scaled by 1/8 -- exact in bf16)
  bf16x8 qA[2][2];
#pragma unroll
  for (int nt = 0; nt < 2; ++nt) {
    const char* qrow = qbb + (size_t)(qb + 16 * nt + qlo) * 2048;
#pragma unroll
    for (int ks = 0; ks < 2; ++ks) {
      qA[nt][ks] = *(const bf16x8*)(qrow + ks * 64 + hi * 16);
#pragma unroll
      for (int i = 0; i < 8; ++i)
        qA[nt][ks][i] = (bf16)(0.125f * (float)qA[nt][ks][i]);
    }
  }

  f32x4 lacc[2] = {};
  f32x4 O[2][4] = {};

  for (int kt = kbeg; kt < kend; ++kt) {
    // direct fragment loads (coalesced 1KB each; L2-resident)
    const char* kT = kfb + (size_t)kt * 8192;
    const char* vT = vfb + (size_t)kt * 8192;
    bf16x8 kFr[2][4], vF[2][4];
#pragma unroll
    for (int ks = 0; ks < 2; ++ks)
#pragma unroll
      for (int t = 0; t < 4; ++t)
        kFr[ks][t] = *(const bf16x8*)(kT + (t * 2 + ks) * 1024);
#pragma unroll
    for (int ks = 0; ks < 2; ++ks)
#pragma unroll
      for (int dt = 0; dt < 4; ++dt)
        vF[ks][dt] = *(const bf16x8*)(vT + (dt * 2 + ks) * 1024);

    // QK^T swapped: sc[nt][t] rows = k (16t+4hi+j), col = q (16nt+qlo)
    f32x4 sc[2][4] = {};
#pragma unroll
    for (int ks = 0; ks < 2; ++ks)
#pragma unroll
      for (int t = 0; t < 4; ++t) {
        sc[0][t] = __builtin_amdgcn_mfma_f32_16x16x32_bf16(
            kFr[ks][t], qA[0][ks], sc[0][t], 0, 0, 0);
        sc[1][t] = __builtin_amdgcn_mfma_f32_16x16x32_bf16(
            kFr[ks][t], qA[1][ks], sc[1][t], 0, 0, 0);
      }

    if (kt * 64 < q0 + 128) {  // mask k <= q in overlapping tiles
      const int k0t = kt * 64;
#pragma unroll
      for (int nt = 0; nt < 2; ++nt)
#pragma unroll
        for (int t = 0; t < 4; ++t)
#pragma unroll
          for (int j = 0; j < 4; ++j) {
            const int kk = k0t + t * 16 + 4 * hi + j;
            const int qq = qb + 16 * nt + qlo;
            if (kk <= qq) sc[nt][t][j] = -1e30f;
          }
    }

    // P = exp(s - 8) = exp2(s*log2e - 8*log2e); masked -> exp2(-inf) = 0
#pragma unroll
    for (int nt = 0; nt < 2; ++nt) {
      unsigned int W[4][2];
#pragma unroll
      for (int t = 0; t < 4; ++t)
#pragma unroll
        for (int p = 0; p < 2; ++p)
          W[t][p] = packbf(
              exp2f(fmaf(sc[nt][t][2 * p], ATTN_LOG2E, ATTN_MBIAS)),
              exp2f(fmaf(sc[nt][t][2 * p + 1], ATTN_LOG2E, ATTN_MBIAS)));
#pragma unroll
      for (int ks = 0; ks < 2; ++ks) {
        uintx4 w4;
#pragma unroll
        for (int p = 0; p < 2; ++p) {
          unsigned int f, s;
          xchg_p(W[2 * ks][p], W[2 * ks + 1][p], hi, f, s);
          w4[p] = f;
          w4[2 + p] = s;
        }
        const bf16x8 pA = __builtin_bit_cast(bf16x8, w4);
        lacc[nt] = __builtin_amdgcn_mfma_f32_16x16x32_bf16(pA, onesB, lacc[nt],
                                                           0, 0, 0);
#pragma unroll
        for (int dt = 0; dt < 4; ++dt)
          O[nt][dt] = __builtin_amdgcn_mfma_f32_16x16x32_bf16(
              pA, vF[ks][dt], O[nt][dt], 0, 0, 0);
      }
    }
  }

  if (slot == 3) {
    // final: normalized write (O rows 4*hi+j; lacc[j] same rows)
#pragma unroll
    for (int nt = 0; nt < 2; ++nt)
#pragma unroll
      for (int j = 0; j < 4; ++j) {
        const float linv = (lacc[nt][j] > 0.f) ? 1.f / lacc[nt][j] : 0.f;
        const int qg = qb + 16 * nt + 4 * hi + j;
#pragma unroll
        for (int dt = 0; dt < 4; ++dt)
          ao[(size_t)(b * 2048 + qg) * 1024 + h * 64 + dt * 16 + qlo] =
              (bf16)(O[nt][dt][j] * linv);
      }
  } else {
    // partial: unnormalized O (bf16) + l (f32); fixed m -> combine is a sum
    const int qtbh = jq * 32 + bh;
#pragma unroll
    for (int nt = 0; nt < 2; ++nt)
#pragma unroll
      for (int j = 0; j < 4; ++j) {
        const int r = w * 32 + 16 * nt + 4 * hi + j;  // row within q-tile
#pragma unroll
        for (int dt = 0; dt < 4; ++dt) {
          const bf16 vv = (bf16)O[nt][dt][j];
          if (slot == 0)
            ao[(size_t)(b * 2048 + q0 + r) * 1024 + h * 64 + dt * 16 + qlo] =
                vv;
          else {
            bf16* sc_ = (slot == 1) ? sc1 : sc2;
            sc_[(size_t)(qtbh * 128 + r) * 64 + dt * 16 + qlo] = vv;
          }
        }
      }
    if (qlo == 0) {
#pragma unroll
      for (int nt = 0; nt < 2; ++nt)
#pragma unroll
        for (int j = 0; j < 4; ++j)
          lbuf[slot * 49152 + qtbh * 128 + (w * 32 + 16 * nt + 4 * hi + j)] =
              lacc[nt][j];
    }
  }
}

// ---------------- combine (bid<384) + vmean (bid>=384) ----------------
__global__ __launch_bounds__(256) void combine_kernel(
    const bf16* __restrict__ sc1, const bf16* __restrict__ sc2,
    const float* __restrict__ lbuf, const bf16* __restrict__ vfr,
    bf16* __restrict__ ao) {
  const int bid = blockIdx.x;
  if (bid >= 384) {  // vmean part
    const int tid = threadIdx.x;
    const int lane = tid & 63, w = tid >> 6;
    const int gw = (bid - 384) * 4 + w;  // 0..127
    const int bh = gw >> 2, dt = gw & 3;
    const int b = bh >> 4, h = bh & 15;
    const char* vfb = (const char*)vfr + (size_t)bh * 262144 + lane * 16;
    float s = 0.f;
    for (int kt = 0; kt < 32; ++kt) {
#pragma unroll
      for (int ks = 0; ks < 2; ++ks) {
        const bf16x8 v =
            *(const bf16x8*)(vfb + (size_t)kt * 8192 + (dt * 2 + ks) * 1024);
#pragma unroll
        for (int e = 0; e < 8; ++e) s += (float)v[e];
      }
    }
    s += __shfl_xor(s, 16);
    s += __shfl_xor(s, 32);
    if ((lane >> 4) == 0)
      ao[(size_t)(b * 2048 + 2047) * 1024 + h * 64 + dt * 16 + lane] =
          (bf16)(s * (1.f / 2048.f));
    return;
  }

  const int qtbh = bid;  // jq*32 + bh, jq in 0..11
  const int jq = qtbh >> 5, bh = qtbh & 31;
  const int b = bh >> 4, h = bh & 15;
  const int t = threadIdx.x;
  const int r = t >> 1;
  const int c0 = (t & 1) * 32;
  const bool three = (jq < 8);

  float l = lbuf[qtbh * 128 + r] + lbuf[49152 + qtbh * 128 + r];
  if (three) l += lbuf[98304 + qtbh * 128 + r];
  const float linv = (l > 0.f) ? 1.f / l : 0.f;

  bf16* arow = ao + ((size_t)(b * 2048 + jq * 128 + r) * 1024 + h * 64 + c0);
  const bf16* s1row = sc1 + ((size_t)(qtbh * 128 + r) * 64 + c0);
  const bf16* s2row = sc2 + ((size_t)(qtbh * 128 + r) * 64 + c0);
#pragma unroll
  for (int i = 0; i < 4; ++i) {
    const bf16x8 o0 = *(const bf16x8*)(arow + i * 8);
    const bf16x8 o1 = *(const bf16x8*)(s1row + i * 8);
    bf16x8 o2;
    if (three) o2 = *(const bf16x8*)(s2row + i * 8);
    bf16x8 o;
#pragma unroll
    for (int j = 0; j < 8; ++j) {
      float acc = (float)o0[j] + (float)o1[j];
      if (three) acc += (float)o2[j];
      o[j] = (bf16)(acc * linv);
    }
    *(bf16x8*)(arow + i * 8) = o;
  }
}

extern "C" void kernel_launch(void* const* d_in, const int* in_sizes, int n_in,
                              void* d_out, int out_size, void* d_ws,
                              size_t ws_size, hipStream_t stream) {
  const float* x  = (const float*)d_in[0];
  const float* wq = (const float*)d_in[2];
  const float* bq = (const float*)d_in[3];
  const float* wk = (const float*)d_in[4];
  const float* bk = (const float*)d_in[5];
  const float* wv = (const float*)d_in[6];
  const float* bv = (const float*)d_in[7];
  const float* wo = (const float*)d_in[8];
  const float* bo = (const float*)d_in[9];
  float* out = (float*)d_out;

  if (ws_size < (size_t)25165824 * 2) return;  // need ~48 MiB of scratch

  bf16* ws    = (bf16*)d_ws;
  bf16* xb    = ws;                     // scratch region: sc1 + lbuf
  bf16* wqkvT = xb + 4194304;           // [3072][1024]; reused: sc2
  bf16* woT   = wqkvT + 3145728;        // [1024][1024]
  bf16* qfp   = woT + 1048576;          // [4096][1024] flat
  bf16* kfrag = qfp + 4194304;          // KF fragment layout, 8 MiB
  bf16* vfrag = kfrag + 4194304;        // VF fragment layout, 8 MiB
  bf16* aop   = vfrag + 4194304;        // [4096][1024] flat

  // partial scratch (xb region unused by GEMMs now; wqkvT dead after QKV):
  bf16*  sc1  = xb;                        // 12qt*32bh*128*64 bf16 = 6.29 MiB
  float* lbuf = (float*)(xb + 3145728);    // 3*49152 f32 = 576 KiB
  bf16*  sc2  = wqkvT;                     // 8qt*32bh*128*64 bf16 = 4.19 MiB

  prep_kernel<<<1024, 256, 0, stream>>>(wq, wk, wv, wo, wqkvT);

  gemm_qkv<<<512, 256, 0, stream>>>(x, wqkvT, bq, bk, bv, qfp, kfrag, vfrag);
  attn_kernel<<<1152, 256, 0, stream>>>(qfp, kfrag, vfrag, aop, sc1, sc2, lbuf);
  combine_kernel<<<416, 256, 0, stream>>>(sc1, sc2, lbuf, vfrag, aop);
  gemm_out<<<512, 256, 0, stream>>>(aop, woT, bo, out);
}

// Round 19
// 103.101 us; speedup vs baseline: 1.0510x; 1.0510x over previous
//
#include <hip/hip_runtime.h>
#include <hip/hip_bf16.h>

// MaskedSelfAttention: B=2, S=2048, D=1024, H=16, depth=64.
// prep(convert x + transpose weights) -> QKV GEMM (128x192, double-buffered
// LDS, fragment-layout K/V epilogue) -> flash attn (LDS-free, fixed-max
// softmax, 1152 k-split chunks) -> combine+vmean -> out GEMM (64x128,
// double-buffered).
// R19: revert R18's fused convert (serial reg-staging regressed 33->47us,
// FETCH 68MB). NEW: both GEMMs double-buffer LDS with STAGE(t+1) issued
// BEFORE compute, vmcnt(0)+barrier at end-of-iter (R2's attn pattern) --
// removes the ~50% drain-before-compute stall the GEMMs carried all session.

using bf16   = __bf16;
using bf16x2 = __attribute__((ext_vector_type(2))) __bf16;
using bf16x4 = __attribute__((ext_vector_type(4))) __bf16;
using bf16x8 = __attribute__((ext_vector_type(8))) __bf16;
using f32x4  = __attribute__((ext_vector_type(4))) float;
using uintx2 = __attribute__((ext_vector_type(2))) unsigned int;
using uintx4 = __attribute__((ext_vector_type(4))) unsigned int;

#define ATTN_LOG2E 1.4426950408889634f
#define ATTN_MBIAS (-11.541560327111707f)  // -8 * log2(e)

__device__ __forceinline__ void load_lds16(const void* g, void* l) {
  __builtin_amdgcn_global_load_lds(
      (const __attribute__((address_space(1))) void*)g,
      (__attribute__((address_space(3))) void*)l, 16, 0, 0);
}

__device__ __forceinline__ unsigned int packbf(float a, float b) {
  bf16x2 v;
  v[0] = (bf16)a;
  v[1] = (bf16)b;
  return __builtin_bit_cast(unsigned int, v);
}

// Redistribute packed P words across hi-groups (in-register P, R4).
__device__ __forceinline__ void xchg_p(unsigned int u, unsigned int v, int hi,
                                       unsigned int& f, unsigned int& s) {
#if __has_builtin(__builtin_amdgcn_permlane32_swap) && \
    __has_builtin(__builtin_amdgcn_permlane16_swap)
  uintx2 ab = __builtin_amdgcn_permlane32_swap(u, v, false, false);
  uintx2 fs = __builtin_amdgcn_permlane16_swap(ab[0], ab[1], false, false);
  f = fs[0];
  s = fs[1];
#else
  unsigned int a = (hi < 2) ? u : (unsigned int)__shfl_xor((int)v, 32);
  unsigned int b = (hi < 2) ? (unsigned int)__shfl_xor((int)u, 32) : v;
  unsigned int a16 = (unsigned int)__shfl_xor((int)a, 16);
  unsigned int b16 = (unsigned int)__shfl_xor((int)b, 16);
  f = (hi & 1) ? b16 : a;
  s = (hi & 1) ? b : a16;
#endif
}

// attn chunk table: jq | kbeg<<8 | kend<<16 | slot<<24
__device__ const unsigned int kChunkTab[36] = {
    0u  | (0u << 8)  | (11u << 16) | (0u << 24),   // 11
    0u  | (11u << 8) | (22u << 16) | (1u << 24),   // 11
    0u  | (22u << 8) | (32u << 16) | (2u << 24),   // 10
    1u  | (2u << 8)  | (12u << 16) | (0u << 24),   // 10
    1u  | (12u << 8) | (22u << 16) | (1u << 24),   // 10
    1u  | (22u << 8) | (32u << 16) | (2u << 24),   // 10
    2u  | (4u << 8)  | (14u << 16) | (0u << 24),   // 10
    2u  | (14u << 8) | (23u << 16) | (1u << 24),   // 9
    2u  | (23u << 8) | (32u << 16) | (2u << 24),   // 9
    3u  | (6u << 8)  | (15u << 16) | (0u << 24),   // 9
    3u  | (15u << 8) | (24u << 16) | (1u << 24),   // 9
    4u  | (8u << 8)  | (16u << 16) | (0u << 24),   // 8
    4u  | (16u << 8) | (24u << 16) | (1u << 24),   // 8
    4u  | (24u << 8) | (32u << 16) | (2u << 24),   // 8
    8u  | (16u << 8) | (24u << 16) | (0u << 24),   // 8
    8u  | (24u << 8) | (32u << 16) | (1u << 24),   // 8
    12u | (24u << 8) | (32u << 16) | (3u << 24),   // 8 final
    3u  | (24u << 8) | (32u << 16) | (2u << 24),   // 8
    5u  | (10u << 8) | (18u << 16) | (0u << 24),   // 8
    5u  | (18u << 8) | (25u << 16) | (1u << 24),   // 7
    5u  | (25u << 8) | (32u << 16) | (2u << 24),   // 7
    6u  | (12u << 8) | (19u << 16) | (0u << 24),   // 7
    6u  | (19u << 8) | (26u << 16) | (1u << 24),   // 7
    9u  | (18u << 8) | (25u << 16) | (0u << 24),   // 7
    9u  | (25u << 8) | (32u << 16) | (1u << 24),   // 7
    6u  | (26u << 8) | (32u << 16) | (2u << 24),   // 6
    7u  | (14u << 8) | (20u << 16) | (0u << 24),   // 6
    7u  | (20u << 8) | (26u << 16) | (1u << 24),   // 6
    7u  | (26u << 8) | (32u << 16) | (2u << 24),   // 6
    10u | (20u << 8) | (26u << 16) | (0u << 24),   // 6
    10u | (26u << 8) | (32u << 16) | (1u << 24),   // 6
    13u | (26u << 8) | (32u << 16) | (3u << 24),   // 6 final
    11u | (22u << 8) | (27u << 16) | (0u << 24),   // 5
    11u | (27u << 8) | (32u << 16) | (1u << 24),   // 5
    14u | (28u << 8) | (32u << 16) | (3u << 24),   // 4 final
    15u | (30u << 8) | (32u << 16) | (3u << 24)};  // 2 final

// ---------------- prep: convert x + transpose 4 weights ----------------
__global__ __launch_bounds__(256) void prep_kernel(
    const float* __restrict__ x, bf16* __restrict__ xb,
    const float* __restrict__ wq, const float* __restrict__ wk,
    const float* __restrict__ wv, const float* __restrict__ wo,
    bf16* __restrict__ wT) {
  const int t = threadIdx.x;
  int bid = blockIdx.x;
  if (bid < 4096) {  // convert x: f32 -> bf16
    const int i = (bid * 256 + t) * 4;
    const float4 v = *(const float4*)(x + i);
    bf16x4 o;
    o[0] = (bf16)v.x; o[1] = (bf16)v.y; o[2] = (bf16)v.z; o[3] = (bf16)v.w;
    *(bf16x4*)(xb + i) = o;
    return;
  }
  bid -= 4096;
  const int sel = bid >> 8;  // 0..3 : wq wk wv wo
  const float* w = (sel == 0) ? wq : (sel == 1) ? wk : (sel == 2) ? wv : wo;
  bf16* out = wT + (size_t)sel * 1048576;
  __shared__ float tile[64][65];
  const int n0 = (bid & 15) * 64;
  const int k0 = ((bid >> 4) & 15) * 64;
#pragma unroll
  for (int p = 0; p < 4; ++p) {
    const int row = p * 16 + (t >> 4);
    const int c4  = (t & 15) * 4;
    const float4 v = *(const float4*)&w[(size_t)(k0 + row) * 1024 + n0 + c4];
    tile[row][c4 + 0] = v.x; tile[row][c4 + 1] = v.y;
    tile[row][c4 + 2] = v.z; tile[row][c4 + 3] = v.w;
  }
  __syncthreads();
#pragma unroll
  for (int p = 0; p < 4; ++p) {
    const int rn = p * 16 + (t >> 4);
    const int c4 = (t & 15) * 4;
    bf16x4 o;
#pragma unroll
    for (int j = 0; j < 4; ++j) o[j] = (bf16)tile[c4 + j][rn];
    *(bf16x4*)&out[(size_t)(n0 + rn) * 1024 + k0 + c4] = o;
  }
}

// ---------------- QKV GEMM: 128x192 tiles, double-buffered LDS ----------
// C = A[4096][1024] * Bt[3072][1024]^T; epilogue scatters Q flat / K frag /
// V frag (+bias). STAGE(kt+1) issued before compute; drain at end-of-iter.
__global__ __launch_bounds__(256, 2) void gemm_qkv(
    const bf16* __restrict__ A, const bf16* __restrict__ Bt,
    const float* __restrict__ bias0, const float* __restrict__ bias1,
    const float* __restrict__ bias2, bf16* __restrict__ qf,
    bf16* __restrict__ kfr, bf16* __restrict__ vfr) {
  // buf b at b*40960: sA 16KB | sB 24KB.  2 x 40KB x 2 blocks = 160KB/CU.
  __shared__ __align__(16) char smem[81920];
  const int tid = threadIdx.x;
  const int lane = tid & 63;
  const int qlo = lane & 15;
  const int hi = lane >> 4;
  const int w = tid >> 6;
  const int wm = w >> 1, wn = w & 1;
  const int bid = blockIdx.x;
  const int m0 = (bid >> 4) * 128;
  const int n0 = (bid & 15) * 192;

  const char* Ab = (const char*)A;
  const char* Bb = (const char*)Bt;
  const int r_ = tid >> 3;
  size_t srcA[4], srcB[6];
#pragma unroll
  for (int i = 0; i < 4; ++i) {
    const int r = i * 32 + r_;
    const int cg = (tid & 7) ^ (r & 7);
    srcA[i] = (size_t)(m0 + r) * 2048 + cg * 16;
  }
#pragma unroll
  for (int i = 0; i < 6; ++i) {
    const int r = i * 32 + r_;
    const int cg = (tid & 7) ^ (r & 7);
    srcB[i] = (size_t)(n0 + r) * 2048 + cg * 16;
  }

  f32x4 acc[4][6] = {};

  auto STAGE = [&](int kt, int buf) {
    const size_t kb = (size_t)kt * 128;
    char* dA = smem + buf * 40960;
    char* dB = dA + 16384;
#pragma unroll
    for (int i = 0; i < 4; ++i)
      load_lds16(Ab + srcA[i] + kb, dA + i * 4096 + tid * 16);
#pragma unroll
    for (int i = 0; i < 6; ++i)
      load_lds16(Bb + srcB[i] + kb, dB + i * 4096 + tid * 16);
  };

  STAGE(0, 0);
  asm volatile("s_waitcnt vmcnt(0)" ::: "memory");
  __syncthreads();

  for (int kt = 0; kt < 16; ++kt) {
    const int cur = kt & 1;
    if (kt + 1 < 16) STAGE(kt + 1, cur ^ 1);

    const char* sA = smem + cur * 40960;
    const char* sB = sA + 16384;
#pragma unroll
    for (int ks = 0; ks < 2; ++ks) {
      const int g = hi + 4 * ks;
      bf16x8 aF[4], bF[6];
#pragma unroll
      for (int mi = 0; mi < 4; ++mi) {
        const int ra = wm * 64 + mi * 16 + qlo;
        aF[mi] = *(const bf16x8*)(sA + ra * 128 + ((g ^ (ra & 7)) << 4));
      }
#pragma unroll
      for (int ni = 0; ni < 6; ++ni) {
        const int rb = wn * 96 + ni * 16 + qlo;
        bF[ni] = *(const bf16x8*)(sB + rb * 128 + ((g ^ (rb & 7)) << 4));
      }
#pragma unroll
      for (int mi = 0; mi < 4; ++mi)
#pragma unroll
        for (int ni = 0; ni < 6; ++ni)
          acc[mi][ni] = __builtin_amdgcn_mfma_f32_16x16x32_bf16(
              aF[mi], bF[ni], acc[mi][ni], 0, 0, 0);
    }
    if (kt + 1 < 16) {
      asm volatile("s_waitcnt vmcnt(0)" ::: "memory");
      __syncthreads();
    }
  }

#pragma unroll
  for (int mi = 0; mi < 4; ++mi) {
#pragma unroll
    for (int ni = 0; ni < 6; ++ni) {
      const int n  = n0 + wn * 96 + ni * 16 + qlo;
      const int mb = m0 + wm * 64 + mi * 16 + 4 * hi;
      const f32x4 v = acc[mi][ni];
      const float bias =
          (n < 1024) ? bias0[n] : ((n < 2048) ? bias1[n - 1024] : bias2[n - 2048]);
      if (n < 1024) {  // Q flat
#pragma unroll
        for (int j = 0; j < 4; ++j)
          qf[(size_t)(mb + j) * 1024 + n] = (bf16)(v[j] + bias);
      } else if (n < 2048) {  // K fragment layout
        const int dg = n - 1024;
        const int hh = dg >> 6, d = dg & 63;
        const int ks = d >> 5, hl = (d >> 3) & 3, e = d & 7;
        const int bb = mb >> 11, sl = mb & 2047;
        const int ktt = sl >> 6, tt = (sl >> 4) & 3, ql = sl & 15;
        bf16* dst = kfr +
                    ((((size_t)(bb * 16 + hh) * 32 + ktt) * 4 + tt) * 2 + ks) *
                        512 +
                    (hl * 16 + ql) * 8 + e;
#pragma unroll
        for (int j = 0; j < 4; ++j) dst[j * 8] = (bf16)(v[j] + bias);
      } else {  // V fragment layout (8B packed store)
        const int dg = n - 2048;
        const int hh = dg >> 6, d = dg & 63;
        const int dt = d >> 4, dc = d & 15;
        const int bb = mb >> 11, sl = mb & 2047;
        const int ktt = sl >> 6, ks = (sl >> 5) & 1, hl = (sl >> 3) & 3,
                  e0 = sl & 7;
        bf16x4 pk;
#pragma unroll
        for (int j = 0; j < 4; ++j) pk[j] = (bf16)(v[j] + bias);
        *(bf16x4*)(vfr +
                   ((((size_t)(bb * 16 + hh) * 32 + ktt) * 4 + dt) * 2 + ks) *
                       512 +
                   (hl * 16 + dc) * 8 + e0) = pk;
      }
    }
  }
}

// ---------------- out GEMM: 64x128 tiles, double-buffered LDS ------------
__global__ __launch_bounds__(256, 2) void gemm_out(
    const bf16* __restrict__ A, const bf16* __restrict__ Bt,
    const float* __restrict__ bias0, float* __restrict__ fout) {
  // buf b at b*24576: sA 8KB | sB 16KB
  __shared__ __align__(16) char smem[49152];
  const int tid = threadIdx.x;
  const int lane = tid & 63;
  const int qlo = lane & 15;
  const int hi = lane >> 4;
  const int w = tid >> 6;
  const int wm = w >> 1, wn = w & 1;  // 2m x 2n waves
  const int bid = blockIdx.x;
  const int m0 = (bid >> 3) * 64;
  const int n0 = (bid & 7) * 128;

  const char* Ab = (const char*)A;
  const char* Bb = (const char*)Bt;
  const int r_ = tid >> 3;
  size_t srcA[2], srcB[4];
#pragma unroll
  for (int i = 0; i < 2; ++i) {
    const int r = r_ + i * 32;
    const int cg = (tid & 7) ^ (r & 7);
    srcA[i] = (size_t)(m0 + r) * 2048 + cg * 16;
  }
#pragma unroll
  for (int i = 0; i < 4; ++i) {
    const int r = r_ + i * 32;
    const int cg = (tid & 7) ^ (r & 7);
    srcB[i] = (size_t)(n0 + r) * 2048 + cg * 16;
  }

  f32x4 acc[2][4] = {};

  auto STAGE = [&](int kt, int buf) {
    const size_t kb = (size_t)kt * 128;
    char* dA = smem + buf * 24576;
    char* dB = dA + 8192;
#pragma unroll
    for (int i = 0; i < 2; ++i)
      load_lds16(Ab + srcA[i] + kb, dA + i * 4096 + tid * 16);
#pragma unroll
    for (int i = 0; i < 4; ++i)
      load_lds16(Bb + srcB[i] + kb, dB + i * 4096 + tid * 16);
  };

  STAGE(0, 0);
  asm volatile("s_waitcnt vmcnt(0)" ::: "memory");
  __syncthreads();

  for (int kt = 0; kt < 16; ++kt) {
    const int cur = kt & 1;
    if (kt + 1 < 16) STAGE(kt + 1, cur ^ 1);

    const char* sA = smem + cur * 24576;
    const char* sB = sA + 8192;
#pragma unroll
    for (int ks = 0; ks < 2; ++ks) {
      const int g = hi + 4 * ks;
      bf16x8 aF[2], bF[4];
#pragma unroll
      for (int mi = 0; mi < 2; ++mi) {
        const int ra = wm * 32 + mi * 16 + qlo;
        aF[mi] = *(const bf16x8*)(sA + ra * 128 + ((g ^ (ra & 7)) << 4));
      }
#pragma unroll
      for (int ni = 0; ni < 4; ++ni) {
        const int rb = wn * 64 + ni * 16 + qlo;
        bF[ni] = *(const bf16x8*)(sB + rb * 128 + ((g ^ (rb & 7)) << 4));
      }
#pragma unroll
      for (int mi = 0; mi < 2; ++mi)
#pragma unroll
        for (int ni = 0; ni < 4; ++ni)
          acc[mi][ni] = __builtin_amdgcn_mfma_f32_16x16x32_bf16(
              aF[mi], bF[ni], acc[mi][ni], 0, 0, 0);
    }
    if (kt + 1 < 16) {
      asm volatile("s_waitcnt vmcnt(0)" ::: "memory");
      __syncthreads();
    }
  }

#pragma unroll
  for (int mi = 0; mi < 2; ++mi) {
#pragma unroll
    for (int ni = 0; ni < 4; ++ni) {
      const int n  = n0 + wn * 64 + ni * 16 + qlo;
      const int mb = m0 + wm * 32 + mi * 16 + 4 * hi;
      const f32x4 v = acc[mi][ni];
      const float bias = bias0[n];
#pragma unroll
      for (int j = 0; j < 4; ++j)
        fout[(size_t)(mb + j) * 1024 + n] = v[j] + bias;
    }
  }
}

// ---------------- flash attention v15 (valid keys: k > q) ----------------
__global__ __launch_bounds__(256, 2) void attn_kernel(
    const bf16* __restrict__ qf, const bf16* __restrict__ kfr,
    const bf16* __restrict__ vfr, bf16* __restrict__ ao,
    bf16* __restrict__ sc1, bf16* __restrict__ sc2,
    float* __restrict__ lbuf) {
  const int tid  = threadIdx.x;
  const int lane = tid & 63;
  const int hi   = lane >> 4;
  const int qlo  = lane & 15;
  const int w    = tid >> 6;
  const int u  = blockIdx.x >> 5;  // 0..35
  const int bh = blockIdx.x & 31;  // same-bh blocks share an XCD's L2
  const int b = bh >> 4, h = bh & 15;

  const unsigned int ent = kChunkTab[u];
  const int jq = ent & 255, kbeg = (ent >> 8) & 255, kend = (ent >> 16) & 255;
  const int slot = ent >> 24;

  const char* kfb = (const char*)kfr + (size_t)bh * 262144 + lane * 16;
  const char* vfb = (const char*)vfr + (size_t)bh * 262144 + lane * 16;
  const char* qbb = (const char*)qf + ((size_t)b * 2048) * 2048 + h * 128;

  bf16x8 onesB;
#pragma unroll
  for (int i = 0; i < 8; ++i) onesB[i] = (bf16)1.0f;

  const int q0 = jq * 128;
  const int qb = q0 + w * 32;

  // Q fragments for 2 column-tiles (pre-scaled by 1/8 -- exact in bf16)
  bf16x8 qA[2][2];
#pragma unroll
  for (int nt = 0; nt < 2; ++nt) {
    const char* qrow = qbb + (size_t)(qb + 16 * nt + qlo) * 2048;
#pragma unroll
    for (int ks = 0; ks < 2; ++ks) {
      qA[nt][ks] = *(const bf16x8*)(qrow + ks * 64 + hi * 16);
#pragma unroll
      for (int i = 0; i < 8; ++i)
        qA[nt][ks][i] = (bf16)(0.125f * (float)qA[nt][ks][i]);
    }
  }

  f32x4 lacc[2] = {};
  f32x4 O[2][4] = {};

  for (int kt = kbeg; kt < kend; ++kt) {
    // direct fragment loads (coalesced 1KB each; L2-resident)
    const char* kT = kfb + (size_t)kt * 8192;
    const char* vT = vfb + (size_t)kt * 8192;
    bf16x8 kFr[2][4], vF[2][4];
#pragma unroll
    for (int ks = 0; ks < 2; ++ks)
#pragma unroll
      for (int t = 0; t < 4; ++t)
        kFr[ks][t] = *(const bf16x8*)(kT + (t * 2 + ks) * 1024);
#pragma unroll
    for (int ks = 0; ks < 2; ++ks)
#pragma unroll
      for (int dt = 0; dt < 4; ++dt)
        vF[ks][dt] = *(const bf16x8*)(vT + (dt * 2 + ks) * 1024);

    // QK^T swapped: sc[nt][t] rows = k (16t+4hi+j), col = q (16nt+qlo)
    f32x4 sc[2][4] = {};
#pragma unroll
    for (int ks = 0; ks < 2; ++ks)
#pragma unroll
      for (int t = 0; t < 4; ++t) {
        sc[0][t] = __builtin_amdgcn_mfma_f32_16x16x32_bf16(
            kFr[ks][t], qA[0][ks], sc[0][t], 0, 0, 0);
        sc[1][t] = __builtin_amdgcn_mfma_f32_16x16x32_bf16(
            kFr[ks][t], qA[1][ks], sc[1][t], 0, 0, 0);
      }

    if (kt * 64 < q0 + 128) {  // mask k <= q in overlapping tiles
      const int k0t = kt * 64;
#pragma unroll
      for (int nt = 0; nt < 2; ++nt)
#pragma unroll
        for (int t = 0; t < 4; ++t)
#pragma unroll
          for (int j = 0; j < 4; ++j) {
            const int kk = k0t + t * 16 + 4 * hi + j;
            const int qq = qb + 16 * nt + qlo;
            if (kk <= qq) sc[nt][t][j] = -1e30f;
          }
    }

    // P = exp(s - 8) = exp2(s*log2e - 8*log2e); masked -> exp2(-inf) = 0
#pragma unroll
    for (int nt = 0; nt < 2; ++nt) {
      unsigned int W[4][2];
#pragma unroll
      for (int t = 0; t < 4; ++t)
#pragma unroll
        for (int p = 0; p < 2; ++p)
          W[t][p] = packbf(
              exp2f(fmaf(sc[nt][t][2 * p], ATTN_LOG2E, ATTN_MBIAS)),
              exp2f(fmaf(sc[nt][t][2 * p + 1], ATTN_LOG2E, ATTN_MBIAS)));
#pragma unroll
      for (int ks = 0; ks < 2; ++ks) {
        uintx4 w4;
#pragma unroll
        for (int p = 0; p < 2; ++p) {
          unsigned int f, s;
          xchg_p(W[2 * ks][p], W[2 * ks + 1][p], hi, f, s);
          w4[p] = f;
          w4[2 + p] = s;
        }
        const bf16x8 pA = __builtin_bit_cast(bf16x8, w4);
        lacc[nt] = __builtin_amdgcn_mfma_f32_16x16x32_bf16(pA, onesB, lacc[nt],
                                                           0, 0, 0);
#pragma unroll
        for (int dt = 0; dt < 4; ++dt)
          O[nt][dt] = __builtin_amdgcn_mfma_f32_16x16x32_bf16(
              pA, vF[ks][dt], O[nt][dt], 0, 0, 0);
      }
    }
  }

  if (slot == 3) {
    // final: normalized write (O rows 4*hi+j; lacc[j] same rows)
#pragma unroll
    for (int nt = 0; nt < 2; ++nt)
#pragma unroll
      for (int j = 0; j < 4; ++j) {
        const float linv = (lacc[nt][j] > 0.f) ? 1.f / lacc[nt][j] : 0.f;
        const int qg = qb + 16 * nt + 4 * hi + j;
#pragma unroll
        for (int dt = 0; dt < 4; ++dt)
          ao[(size_t)(b * 2048 + qg) * 1024 + h * 64 + dt * 16 + qlo] =
              (bf16)(O[nt][dt][j] * linv);
      }
  } else {
    // partial: unnormalized O (bf16) + l (f32); fixed m -> combine is a sum
    const int qtbh = jq * 32 + bh;
#pragma unroll
    for (int nt = 0; nt < 2; ++nt)
#pragma unroll
      for (int j = 0; j < 4; ++j) {
        const int r = w * 32 + 16 * nt + 4 * hi + j;  // row within q-tile
#pragma unroll
        for (int dt = 0; dt < 4; ++dt) {
          const bf16 vv = (bf16)O[nt][dt][j];
          if (slot == 0)
            ao[(size_t)(b * 2048 + q0 + r) * 1024 + h * 64 + dt * 16 + qlo] =
                vv;
          else {
            bf16* sc_ = (slot == 1) ? sc1 : sc2;
            sc_[(size_t)(qtbh * 128 + r) * 64 + dt * 16 + qlo] = vv;
          }
        }
      }
    if (qlo == 0) {
#pragma unroll
      for (int nt = 0; nt < 2; ++nt)
#pragma unroll
        for (int j = 0; j < 4; ++j)
          lbuf[slot * 49152 + qtbh * 128 + (w * 32 + 16 * nt + 4 * hi + j)] =
              lacc[nt][j];
    }
  }
}

// ---------------- combine (bid<384) + vmean (bid>=384) ----------------
__global__ __launch_bounds__(256) void combine_kernel(
    const bf16* __restrict__ sc1, const bf16* __restrict__ sc2,
    const float* __restrict__ lbuf, const bf16* __restrict__ vfr,
    bf16* __restrict__ ao) {
  const int bid = blockIdx.x;
  if (bid >= 384) {  // vmean part
    const int tid = threadIdx.x;
    const int lane = tid & 63, w = tid >> 6;
    const int gw = (bid - 384) * 4 + w;  // 0..127
    const int bh = gw >> 2, dt = gw & 3;
    const int b = bh >> 4, h = bh & 15;
    const char* vfb = (const char*)vfr + (size_t)bh * 262144 + lane * 16;
    float s = 0.f;
    for (int kt = 0; kt < 32; ++kt) {
#pragma unroll
      for (int ks = 0; ks < 2; ++ks) {
        const bf16x8 v =
            *(const bf16x8*)(vfb + (size_t)kt * 8192 + (dt * 2 + ks) * 1024);
#pragma unroll
        for (int e = 0; e < 8; ++e) s += (float)v[e];
      }
    }
    s += __shfl_xor(s, 16);
    s += __shfl_xor(s, 32);
    if ((lane >> 4) == 0)
      ao[(size_t)(b * 2048 + 2047) * 1024 + h * 64 + dt * 16 + lane] =
          (bf16)(s * (1.f / 2048.f));
    return;
  }

  const int qtbh = bid;  // jq*32 + bh, jq in 0..11
  const int jq = qtbh >> 5, bh = qtbh & 31;
  const int b = bh >> 4, h = bh & 15;
  const int t = threadIdx.x;
  const int r = t >> 1;
  const int c0 = (t & 1) * 32;
  const bool three = (jq < 8);

  float l = lbuf[qtbh * 128 + r] + lbuf[49152 + qtbh * 128 + r];
  if (three) l += lbuf[98304 + qtbh * 128 + r];
  const float linv = (l > 0.f) ? 1.f / l : 0.f;

  bf16* arow = ao + ((size_t)(b * 2048 + jq * 128 + r) * 1024 + h * 64 + c0);
  const bf16* s1row = sc1 + ((size_t)(qtbh * 128 + r) * 64 + c0);
  const bf16* s2row = sc2 + ((size_t)(qtbh * 128 + r) * 64 + c0);
#pragma unroll
  for (int i = 0; i < 4; ++i) {
    const bf16x8 o0 = *(const bf16x8*)(arow + i * 8);
    const bf16x8 o1 = *(const bf16x8*)(s1row + i * 8);
    bf16x8 o2;
    if (three) o2 = *(const bf16x8*)(s2row + i * 8);
    bf16x8 o;
#pragma unroll
    for (int j = 0; j < 8; ++j) {
      float acc = (float)o0[j] + (float)o1[j];
      if (three) acc += (float)o2[j];
      o[j] = (bf16)(acc * linv);
    }
    *(bf16x8*)(arow + i * 8) = o;
  }
}

extern "C" void kernel_launch(void* const* d_in, const int* in_sizes, int n_in,
                              void* d_out, int out_size, void* d_ws,
                              size_t ws_size, hipStream_t stream) {
  const float* x  = (const float*)d_in[0];
  const float* wq = (const float*)d_in[2];
  const float* bq = (const float*)d_in[3];
  const float* wk = (const float*)d_in[4];
  const float* bk = (const float*)d_in[5];
  const float* wv = (const float*)d_in[6];
  const float* bv = (const float*)d_in[7];
  const float* wo = (const float*)d_in[8];
  const float* bo = (const float*)d_in[9];
  float* out = (float*)d_out;

  if (ws_size < (size_t)25165824 * 2) return;  // need ~48 MiB of scratch

  bf16* ws    = (bf16*)d_ws;
  bf16* xb    = ws;                     // [4096][1024]; reused: sc1+lbuf
  bf16* wqkvT = xb + 4194304;           // [3072][1024]; reused: sc2
  bf16* woT   = wqkvT + 3145728;        // [1024][1024]
  bf16* qfp   = woT + 1048576;          // [4096][1024] flat
  bf16* kfrag = qfp + 4194304;          // KF fragment layout, 8 MiB
  bf16* vfrag = kfrag + 4194304;        // VF fragment layout, 8 MiB
  bf16* aop   = vfrag + 4194304;        // [4096][1024] flat

  // partial scratch (xb dead after QKV GEMM; wqkvT dead after QKV GEMM):
  bf16*  sc1  = xb;                        // 12qt*32bh*128*64 bf16 = 6.29 MiB
  float* lbuf = (float*)(xb + 3145728);    // 3*49152 f32 = 576 KiB
  bf16*  sc2  = wqkvT;                     // 8qt*32bh*128*64 bf16 = 4.19 MiB

  prep_kernel<<<5120, 256, 0, stream>>>(x, xb, wq, wk, wv, wo, wqkvT);

  gemm_qkv<<<512, 256, 0, stream>>>(xb, wqkvT, bq, bk, bv, qfp, kfrag, vfrag);
  attn_kernel<<<1152, 256, 0, stream>>>(qfp, kfrag, vfrag, aop, sc1, sc2, lbuf);
  combine_kernel<<<416, 256, 0, stream>>>(sc1, sc2, lbuf, vfrag, aop);
  gemm_out<<<512, 256, 0, stream>>>(aop, woT, bo, out);
}